// Round 15
// baseline (3574.884 us; speedup 1.0000x reference)
//
#include <hip/hip_runtime.h>
#include <hip/hip_bf16.h>
#include <math.h>

typedef __hip_bfloat16 bf16;
typedef __attribute__((ext_vector_type(8))) short short8;
typedef __attribute__((ext_vector_type(4))) float f32x4;
typedef unsigned short u16;

__device__ inline u16 f2bu(float f) {            // f32 -> bf16 bits, RNE
  unsigned u = __builtin_bit_cast(unsigned, f);
  u += 0x7fffu + ((u >> 16) & 1u);
  return (u16)(u >> 16);
}

// ============================ dtype autodetect ============================
__global__ void detect_k(const u16* __restrict__ u, int* __restrict__ flag) {
  if (threadIdx.x == 0 && blockIdx.x == 0) {
    int wild = 0;
    for (int i = 0; i < 256; i++) {
      int e = (u[i] >> 7) & 0xFF;
      if (e < 0x66 || e > 0x8A) wild++;
    }
    *flag = (wild > 64) ? 1 : 0;  // 1 => inputs are float32
  }
}

__global__ void in2f_k(const void* __restrict__ in, float* __restrict__ out, int n,
                       const int* __restrict__ flag) {
  int i = blockIdx.x * 256 + threadIdx.x;
  if (i >= n) return;
  if (*flag) out[i] = ((const float*)in)[i];
  else       out[i] = __bfloat162float(((const bf16*)in)[i]);
}

__global__ void zero_k(float* __restrict__ p, int n) {
  int i = blockIdx.x * 256 + threadIdx.x;
  if (i < n) p[i] = 0.f;
}

__global__ void zeroi_k(int* __restrict__ p, int n) {
  int i = blockIdx.x * 256 + threadIdx.x;
  if (i < n) p[i] = 0;
}

__global__ void transpose_k(const float* __restrict__ in, float* __restrict__ out,
                            int rows, int cols) {
  int i = blockIdx.x * 256 + threadIdx.x;
  if (i >= rows * cols) return;
  int c = i % cols, r = i / cols;
  out[(size_t)c * rows + r] = in[i];
}

// f32 -> bf16 bits
__global__ void f2b_k(const float* __restrict__ in, u16* __restrict__ out, int n) {
  int i = blockIdx.x * 256 + threadIdx.x;
  if (i < n) out[i] = f2bu(in[i]);
}

// W[K][N] f32 -> Wp[Kpad][N] f32, zero pad
__global__ void padw_k(const float* __restrict__ W, float* __restrict__ Wp,
                       int K, int N, int Kpad) {
  int i = blockIdx.x * 256 + threadIdx.x;
  if (i >= Kpad * N) return;
  int n = i % N, k = i / N;
  Wp[i] = (k < K) ? W[(size_t)k * N + n] : 0.f;
}

// W[KT][Nw] f32 -> WT[Nw][KTpad] bf16 (pad zero)
__global__ void w2bt_k(const float* __restrict__ W, u16* __restrict__ WT,
                       int KT, int Nw, int KTpad) {
  int i = blockIdx.x * 256 + threadIdx.x;
  if (i >= Nw * KTpad) return;
  int kp = i % KTpad, n = i / KTpad;
  WT[i] = (kp < KT) ? f2bu(W[(size_t)kp * Nw + n]) : (u16)0;
}

enum { EPI_NONE = 0, EPI_RELU = 1, EPI_SIG = 2, EPI_CHEB = 3, EPI_SCAT = 4, EPI_UPD = 5 };

// ============================ slow guarded f32 GEMM (K=20 cases) ============================
struct GemmArgs {
  const float* A; const float* Bm; float* C;
  int M, N, K;
};
__global__ __launch_bounds__(256) void gemm_s(GemmArgs g) {
  __shared__ float As[16][65];
  __shared__ float Bs[16][65];
  const int tid = threadIdx.x;
  const int tx = tid & 15, ty = tid >> 4;
  const int bm = blockIdx.y * 64, bn = blockIdx.x * 64;
  float acc[4][4] = {{0.f}};
  for (int k0 = 0; k0 < g.K; k0 += 16) {
#pragma unroll
    for (int i = 0; i < 4; i++) {
      int idx = i * 256 + tid; int c = idx & 15, r = idx >> 4;
      int mm = bm + r, kk = k0 + c;
      As[c][r] = (mm < g.M && kk < g.K) ? g.A[(size_t)mm * g.K + kk] : 0.f;
    }
#pragma unroll
    for (int i = 0; i < 4; i++) {
      int idx = i * 256 + tid; int c = idx & 63, r = idx >> 6;
      int kk = k0 + r, nn = bn + c;
      Bs[r][c] = (kk < g.K && nn < g.N) ? g.Bm[(size_t)kk * g.N + nn] : 0.f;
    }
    __syncthreads();
#pragma unroll
    for (int kk = 0; kk < 16; kk++) {
      float a[4], b[4];
#pragma unroll
      for (int i = 0; i < 4; i++) a[i] = As[kk][ty * 4 + i];
#pragma unroll
      for (int j = 0; j < 4; j++) b[j] = Bs[kk][tx * 4 + j];
#pragma unroll
      for (int i = 0; i < 4; i++)
#pragma unroll
        for (int j = 0; j < 4; j++) acc[i][j] = fmaf(a[i], b[j], acc[i][j]);
    }
    __syncthreads();
  }
#pragma unroll
  for (int i = 0; i < 4; i++) {
    int m = bm + ty * 4 + i;
    if (m >= g.M) continue;
#pragma unroll
    for (int j = 0; j < 4; j++) {
      int n = bn + tx * 4 + j;
      if (n >= g.N) continue;
      g.C[(size_t)m * g.N + n] = acc[i][j];
    }
  }
}

// ============================ fast f32 GEMM (dbuf, BK=32, K%32==0, M%64==0) ==========
struct FGemmArgs {
  const float* A; const float* Bm; const float* bias; float* C;
  int M, N, K, ldb;
  const float* aux0;  // zr (UPD) | H read (SIG enc)
  float* aux1;        // XG (SCAT) | H state (UPD)
  float* aux2;        // h_en base (UPD)
  float* aux3;        // X write (SIG/UPD enc fusion)
  float* aux4;        // XG write (SIG/UPD enc fusion)
  int i0, i1, i2;     // SCAT: C,ldXG | UPD: zr_ld, hdim, t
};

template<int EPI>
__global__ __launch_bounds__(256) void fgemm_k(FGemmArgs g) {
  __shared__ __align__(16) float As[2][32][68];
  __shared__ __align__(16) float Bs[2][32][68];
  const int tid = threadIdx.x;
  const int tx = tid & 15, ty = tid >> 4;
  const int bm = blockIdx.y * 64, bn = blockIdx.x * 64;
  const int ar = tid >> 2, ac = (tid & 3) * 4;
  const int br = tid >> 4, bc = (tid & 15) * 4;
  float acc[4][4] = {{0.f}};

  float4 av0 = *(const float4*)(g.A + (size_t)(bm + ar) * g.K + ac);
  float4 av1 = *(const float4*)(g.A + (size_t)(bm + ar) * g.K + 16 + ac);
  float4 bv0 = *(const float4*)(g.Bm + (size_t)br * g.ldb + bn + bc);
  float4 bv1 = *(const float4*)(g.Bm + (size_t)(16 + br) * g.ldb + bn + bc);
  As[0][ac + 0][ar] = av0.x; As[0][ac + 1][ar] = av0.y;
  As[0][ac + 2][ar] = av0.z; As[0][ac + 3][ar] = av0.w;
  As[0][16 + ac + 0][ar] = av1.x; As[0][16 + ac + 1][ar] = av1.y;
  As[0][16 + ac + 2][ar] = av1.z; As[0][16 + ac + 3][ar] = av1.w;
  *(float4*)&Bs[0][br][bc] = bv0;
  *(float4*)&Bs[0][16 + br][bc] = bv1;
  __syncthreads();

  int cur = 0;
  for (int k0 = 0; k0 < g.K; k0 += 32) {
    const bool has_next = (k0 + 32 < g.K);
    if (has_next) {
      av0 = *(const float4*)(g.A + (size_t)(bm + ar) * g.K + k0 + 32 + ac);
      av1 = *(const float4*)(g.A + (size_t)(bm + ar) * g.K + k0 + 48 + ac);
      bv0 = *(const float4*)(g.Bm + (size_t)(k0 + 32 + br) * g.ldb + bn + bc);
      bv1 = *(const float4*)(g.Bm + (size_t)(k0 + 48 + br) * g.ldb + bn + bc);
    }
#pragma unroll
    for (int kk = 0; kk < 32; kk++) {
      float4 a4 = *(const float4*)&As[cur][kk][ty * 4];
      float4 b4 = *(const float4*)&Bs[cur][kk][tx * 4];
      float a[4] = {a4.x, a4.y, a4.z, a4.w};
      float b[4] = {b4.x, b4.y, b4.z, b4.w};
#pragma unroll
      for (int i = 0; i < 4; i++)
#pragma unroll
        for (int j = 0; j < 4; j++) acc[i][j] = fmaf(a[i], b[j], acc[i][j]);
    }
    if (has_next) {
      int nxt = cur ^ 1;
      As[nxt][ac + 0][ar] = av0.x; As[nxt][ac + 1][ar] = av0.y;
      As[nxt][ac + 2][ar] = av0.z; As[nxt][ac + 3][ar] = av0.w;
      As[nxt][16 + ac + 0][ar] = av1.x; As[nxt][16 + ac + 1][ar] = av1.y;
      As[nxt][16 + ac + 2][ar] = av1.z; As[nxt][16 + ac + 3][ar] = av1.w;
      *(float4*)&Bs[nxt][br][bc] = bv0;
      *(float4*)&Bs[nxt][16 + br][bc] = bv1;
      __syncthreads();
      cur = nxt;
    }
  }
#pragma unroll
  for (int i = 0; i < 4; i++) {
    int m = bm + ty * 4 + i;
#pragma unroll
    for (int j = 0; j < 4; j++) {
      int n = bn + tx * 4 + j;
      if (n >= g.N) continue;
      float v = acc[i][j];
      if (EPI == EPI_NONE) {
        g.C[(size_t)m * g.N + n] = v;
      } else if (EPI == EPI_RELU) {
        g.C[(size_t)m * g.N + n] = fmaxf(v, 0.f);
      } else if (EPI == EPI_CHEB) {
        g.C[(size_t)m * g.N + n] = 2.f * v - (m == n ? 1.f : 0.f);
      } else if (EPI == EPI_SCAT) {
        int bb = n / g.i0, cc = n % g.i0;
        int km = m >> 9;
        int kmap = km + 1 + (km >= 2 ? 1 : 0);
        int node = m & 511;
        g.aux1[((size_t)bb * 512 + node) * g.i1 + (size_t)kmap * g.i0 + cc] = v;
      }
    }
  }
}

// ============================ TM=32 f32 GEMM (dbuf BK=16) =============
// 32x64 tile, 256 threads, 2x4 microtile; 2x blocks vs 64-tile. Same k-order.
template<int EPI>
__global__ __launch_bounds__(256) void fgemm32_k(FGemmArgs g) {
  __shared__ __align__(16) float As[2][16][40];
  __shared__ __align__(16) float Bs[2][16][68];
  const int tid = threadIdx.x;
  const int tx = tid & 15, ty = tid >> 4;
  const int bm = blockIdx.y * 32, bn = blockIdx.x * 64;
  const int ar = tid >> 2, ac = (tid & 3) * 4;
  const int br = tid >> 4, bc = (tid & 15) * 4;
  float acc[2][4] = {{0.f}};

  float4 av, bv;
  if (ar < 32) av = *(const float4*)(g.A + (size_t)(bm + ar) * g.K + ac);
  bv = *(const float4*)(g.Bm + (size_t)br * g.ldb + bn + bc);
  if (ar < 32) {
    As[0][ac + 0][ar] = av.x; As[0][ac + 1][ar] = av.y;
    As[0][ac + 2][ar] = av.z; As[0][ac + 3][ar] = av.w;
  }
  *(float4*)&Bs[0][br][bc] = bv;
  __syncthreads();

  int cur = 0;
  for (int k0 = 0; k0 < g.K; k0 += 16) {
    const bool has_next = (k0 + 16 < g.K);
    if (has_next) {
      if (ar < 32) av = *(const float4*)(g.A + (size_t)(bm + ar) * g.K + k0 + 16 + ac);
      bv = *(const float4*)(g.Bm + (size_t)(k0 + 16 + br) * g.ldb + bn + bc);
    }
#pragma unroll
    for (int kk = 0; kk < 16; kk++) {
      float a0 = As[cur][kk][ty * 2 + 0];
      float a1 = As[cur][kk][ty * 2 + 1];
      float4 b4 = *(const float4*)&Bs[cur][kk][tx * 4];
      float b[4] = {b4.x, b4.y, b4.z, b4.w};
#pragma unroll
      for (int j = 0; j < 4; j++) {
        acc[0][j] = fmaf(a0, b[j], acc[0][j]);
        acc[1][j] = fmaf(a1, b[j], acc[1][j]);
      }
    }
    if (has_next) {
      int nxt = cur ^ 1;
      if (ar < 32) {
        As[nxt][ac + 0][ar] = av.x; As[nxt][ac + 1][ar] = av.y;
        As[nxt][ac + 2][ar] = av.z; As[nxt][ac + 3][ar] = av.w;
      }
      *(float4*)&Bs[nxt][br][bc] = bv;
      __syncthreads();
      cur = nxt;
    }
  }
#pragma unroll
  for (int i = 0; i < 2; i++) {
    int m = bm + ty * 2 + i;
    int node = m & 511, bb = m >> 9;
#pragma unroll
    for (int j = 0; j < 4; j++) {
      int n = bn + tx * 4 + j;
      if (n >= g.N) continue;
      float v = acc[i][j];
      if (EPI == EPI_NONE) {
        g.C[(size_t)m * g.N + n] = v;
      } else if (EPI == EPI_RELU) {
        g.C[(size_t)m * g.N + n] = fmaxf(v, 0.f);
      } else if (EPI == EPI_CHEB) {
        g.C[(size_t)m * g.N + n] = 2.f * v - (m == n ? 1.f : 0.f);
      } else if (EPI == EPI_SCAT) {
        int b2 = n / g.i0, cc = n % g.i0;
        int km = m >> 9;
        int kmap = km + 1 + (km >= 2 ? 1 : 0);
        g.aux1[((size_t)b2 * 512 + node) * g.i1 + (size_t)kmap * g.i0 + cc] = v;
      } else if (EPI == EPI_SIG) {
        v += g.bias[n];
        float sg = 1.f / (1.f + expf(-v));
        g.C[(size_t)m * g.N + n] = sg;
        if (n < 64) {
          float zh = sg * g.aux0[(size_t)m * 64 + n];   // aux0 = H
          g.aux3[(size_t)node * 1088 + bb * 65 + 1 + n] = zh;
          g.aux4[(size_t)m * 416 + 1 + n] = zh;
          g.aux4[(size_t)m * 416 + 196 + n] = zh;
        }
      } else if (EPI == EPI_UPD) {
        v = tanhf(v + g.bias[n]);
        float r = g.aux0[(size_t)m * g.i0 + g.i1 + n];
        float h = r * g.aux1[(size_t)m * g.i1 + n] + (1.f - r) * v;
        g.aux1[(size_t)m * g.i1 + n] = h;
        if (g.aux2)
          g.aux2[(((size_t)bb * 12 + g.i2) * 512 + node) * 64 + n] = h;
        g.aux3[(size_t)node * 1088 + bb * 65 + 1 + n] = h;
        g.aux4[(size_t)m * 416 + 1 + n] = h;
        g.aux4[(size_t)m * 416 + 196 + n] = h;
      }
    }
  }
}

// ============================ plain bf16 MFMA GEMM, dbuf (decoder) ============================
struct MmArgs {
  const u16* A; const u16* BT; int M, N, K;
  const float* bias; float* C;                 // SIG: zr out
  u16* xg;                                     // SCAT dest
  const float* zr; float* state; float* hen;   // UPD
  u16* xtw; u16* xgw;                          // fused XT/XGb writes (SIG/UPD)
  int i0, i1, i2;
};

template<int EPI>
__global__ __launch_bounds__(256) void mm_k(MmArgs g) {
  __shared__ __align__(16) u16 Als[2][64][40];
  __shared__ __align__(16) u16 Bls[2][64][40];
  const int tid = threadIdx.x;
  const int w = tid >> 6, lane = tid & 63;
  const int l15 = lane & 15, lk = lane >> 4;
  const int m0 = blockIdx.y * 64, n0 = blockIdx.x * 64;
  const int srow = tid >> 2, schunk = tid & 3;
  f32x4 acc[4];
#pragma unroll
  for (int j = 0; j < 4; j++) acc[j] = (f32x4){0.f, 0.f, 0.f, 0.f};

  short8 a8 = *(const short8*)(g.A + (size_t)(m0 + srow) * g.K + schunk * 8);
  short8 b8 = (short8){0,0,0,0,0,0,0,0};
  if (n0 + srow < g.N)
    b8 = *(const short8*)(g.BT + (size_t)(n0 + srow) * g.K + schunk * 8);
  *(short8*)&Als[0][srow][schunk * 8] = a8;
  *(short8*)&Bls[0][srow][schunk * 8] = b8;
  __syncthreads();

  int cur = 0;
  for (int k0 = 0; k0 < g.K; k0 += 32) {
    const bool has_next = (k0 + 32 < g.K);
    if (has_next) {
      a8 = *(const short8*)(g.A + (size_t)(m0 + srow) * g.K + k0 + 32 + schunk * 8);
      b8 = (short8){0,0,0,0,0,0,0,0};
      if (n0 + srow < g.N)
        b8 = *(const short8*)(g.BT + (size_t)(n0 + srow) * g.K + k0 + 32 + schunk * 8);
    }
    short8 af = *(const short8*)&Als[cur][w * 16 + l15][lk * 8];
#pragma unroll
    for (int j = 0; j < 4; j++) {
      short8 bf = *(const short8*)&Bls[cur][j * 16 + l15][lk * 8];
      acc[j] = __builtin_amdgcn_mfma_f32_16x16x32_bf16(af, bf, acc[j], 0, 0, 0);
    }
    if (has_next) {
      int nxt = cur ^ 1;
      *(short8*)&Als[nxt][srow][schunk * 8] = a8;
      *(short8*)&Bls[nxt][srow][schunk * 8] = b8;
      __syncthreads();
      cur = nxt;
    }
  }

#pragma unroll
  for (int j = 0; j < 4; j++) {
    int col = n0 + j * 16 + l15;
    if (col >= g.N) continue;
#pragma unroll
    for (int r = 0; r < 4; r++) {
      int row = m0 + w * 16 + lk * 4 + r;
      int node = row & 511, bb = row >> 9;
      float v = acc[j][r];
      if (EPI == EPI_SCAT) {
        int b2 = col / g.i0, cc = col % g.i0;
        int km = row >> 9;
        int kmap = km + 1 + (km >= 2 ? 1 : 0);
        g.xg[((size_t)b2 * 512 + node) * g.i1 + (size_t)kmap * g.i0 + cc] = f2bu(v);
      } else if (EPI == EPI_SIG) {
        v += g.bias[col];
        float sg = 1.f / (1.f + expf(-v));
        g.C[(size_t)row * g.N + col] = sg;
        if (col < 128) {
          float zh = sg * g.state[(size_t)row * 128 + col];
          u16 bv = f2bu(zh);
          g.xtw[((size_t)(bb * 130 + 2 + col)) * 512 + node] = bv;
          g.xgw[(size_t)row * 800 + 2 + col] = bv;
          g.xgw[(size_t)row * 800 + 392 + col] = bv;
        }
      } else if (EPI == EPI_UPD) {
        v = tanhf(v + g.bias[col]);
        float rr = g.zr[(size_t)row * g.i0 + g.i1 + col];
        float h = rr * g.state[(size_t)row * g.i1 + col] + (1.f - rr) * v;
        g.state[(size_t)row * g.i1 + col] = h;
        u16 bv = f2bu(h);
        g.xtw[((size_t)(bb * 130 + 2 + col)) * 512 + node] = bv;
        g.xgw[(size_t)row * 800 + 2 + col] = bv;
        g.xgw[(size_t)row * 800 + 392 + col] = bv;
      }
    }
  }
}

// ============================ model-specific kernels ============================

__global__ void putxe_k(const float* __restrict__ x1, float* __restrict__ X,
                        float* __restrict__ XG) {
  int bn = blockIdx.x * 256 + threadIdx.x;
  if (bn >= 8192) return;
  int n = bn & 511, b = bn >> 9;
  float v = x1[(size_t)b * 6144 + n];
  X[(size_t)n * 1088 + b * 65] = v;
  XG[(size_t)bn * 416 + 0] = v;
  XG[(size_t)bn * 416 + 195] = v;
}

__global__ void putxd_k(const float* __restrict__ yc, u16* __restrict__ XT,
                        u16* __restrict__ XGb) {
  int bn = blockIdx.x * 256 + threadIdx.x;
  if (bn >= 8192) return;
  int n = bn & 511, b = bn >> 9;
  u16 bv = f2bu(yc[(size_t)b * 6144 + n]);
  XT[((size_t)(b * 130 + 1)) * 512 + n] = bv;
  XGb[(size_t)bn * 800 + 1] = bv;
  XGb[(size_t)bn * 800 + 391] = bv;
}

__global__ __launch_bounds__(256) void softmax512_k(const float* __restrict__ Min,
                                                    float* __restrict__ out, int colMajor) {
  int row = blockIdx.x;
  __shared__ float buf[512];
  __shared__ float red[256];
  int tid = threadIdx.x;
  for (int i = tid; i < 512; i += 256)
    buf[i] = colMajor ? Min[(size_t)i * 512 + row] : Min[(size_t)row * 512 + i];
  __syncthreads();
  float mx = -1e30f;
  for (int i = tid; i < 512; i += 256) mx = fmaxf(mx, buf[i]);
  red[tid] = mx; __syncthreads();
  for (int w = 128; w > 0; w >>= 1) { if (tid < w) red[tid] = fmaxf(red[tid], red[tid + w]); __syncthreads(); }
  mx = red[0]; __syncthreads();
  float s = 0.f;
  for (int i = tid; i < 512; i += 256) { float e = expf(buf[i] - mx); buf[i] = e; s += e; }
  red[tid] = s; __syncthreads();
  for (int w = 128; w > 0; w >>= 1) { if (tid < w) red[tid] += red[tid + w]; __syncthreads(); }
  float inv = 1.f / red[0];
  for (int i = tid; i < 512; i += 256) out[(size_t)row * 512 + i] = buf[i] * inv;
}

__global__ __launch_bounds__(256) void attmem_k(const float* __restrict__ query,
    const float* __restrict__ Mem, float* __restrict__ att_out,
    float* __restrict__ hatt, int* __restrict__ ind) {
  __shared__ float sm[20 * 64];
  for (int i = threadIdx.x; i < 20 * 64; i += 256) sm[i] = Mem[i];
  __syncthreads();
  int bn = blockIdx.x * 256 + threadIdx.x;
  if (bn >= 16 * 512) return;
  float q[64];
#pragma unroll
  for (int d = 0; d < 64; d++) q[d] = query[(size_t)bn * 64 + d];
  float lg[20];
  float mx = -1e30f;
#pragma unroll
  for (int m = 0; m < 20; m++) {
    float s = 0.f;
#pragma unroll
    for (int d = 0; d < 64; d++) s = fmaf(q[d], sm[m * 64 + d], s);
    lg[m] = s; mx = fmaxf(mx, s);
  }
  float se = 0.f;
#pragma unroll
  for (int m = 0; m < 20; m++) { lg[m] = expf(lg[m] - mx); se += lg[m]; }
  float inv = 1.f / se;
#pragma unroll
  for (int m = 0; m < 20; m++) {
    lg[m] *= inv;
    att_out[(size_t)bn * 20 + m] = lg[m];
  }
#pragma unroll
  for (int d = 0; d < 64; d++) {
    float s = 0.f;
#pragma unroll
    for (int m = 0; m < 20; m++) s = fmaf(lg[m], sm[m * 64 + d], s);
    hatt[(size_t)bn * 64 + d] = s;
  }
  unsigned used = 0;
  for (int s = 0; s < 20; s++) {
    float bv = -1e30f; int bi = 0;
#pragma unroll
    for (int m = 0; m < 20; m++) {
      bool better = (!((used >> m) & 1u)) && (lg[m] > bv);
      if (better) { bv = lg[m]; bi = m; }
    }
    used |= (1u << bi);
    ind[(size_t)bn * 20 + s] = bi;
  }
}

__global__ void gather_pn_k(const int* __restrict__ ind, const float* __restrict__ Memf,
                            float* __restrict__ pos, float* __restrict__ neg) {
  size_t i = (size_t)blockIdx.x * 256 + threadIdx.x;
  if (i >= (size_t)16 * 512 * 20 * 64) return;
  int d = (int)(i & 63); size_t r = i >> 6;
  int s = (int)(r % 20); size_t bn = r / 20;
  int m = ind[bn * 20 + s];
  float v = Memf[m * 64 + d];
  if (s == 0) pos[bn * 64 + d] = v;
  else neg[(bn * 19 + (size_t)(s - 1)) * 64 + d] = v;
}

__global__ void sinit_k(const float* __restrict__ H, const float* __restrict__ hatt,
                        float* __restrict__ S, u16* __restrict__ XT,
                        u16* __restrict__ XGb) {
  int i = blockIdx.x * 256 + threadIdx.x;
  if (i >= 8192 * 128) return;
  int c = i & 127; int bn = i >> 7;
  int n = bn & 511, b = bn >> 9;
  float v = (c < 64) ? H[(size_t)bn * 64 + c] : hatt[(size_t)bn * 64 + (c - 64)];
  S[i] = v;
  u16 bv = f2bu(v);
  XT[((size_t)(b * 130 + 2 + c)) * 512 + n] = bv;
  XGb[(size_t)bn * 800 + 2 + c] = bv;
  XGb[(size_t)bn * 800 + 392 + c] = bv;
  if (c == 0) {
    XT[((size_t)(b * 130)) * 512 + n] = 0;
  }
}

__global__ __launch_bounds__(256) void att_dot_k(const float* __restrict__ E,
    const float* __restrict__ D, float* __restrict__ partial) {
  int t = blockIdx.y, ch = blockIdx.x;
  const float* e = E + (size_t)t * 524288 + (size_t)ch * 16384;
  const float* d = D + (size_t)ch * 16384;
  float s = 0.f;
  for (int i = threadIdx.x; i < 16384; i += 256) s = fmaf(e[i], d[i], s);
  __shared__ float red[256];
  red[threadIdx.x] = s; __syncthreads();
  for (int w = 128; w > 0; w >>= 1) {
    if (threadIdx.x < w) red[threadIdx.x] += red[threadIdx.x + w];
    __syncthreads();
  }
  if (threadIdx.x == 0) partial[t * 32 + ch] = red[0];
}

// context + projection; computes softmax(att) from partials internally
// (same reduction order as the old att_sm_k -> bit-identical), writes output
// AND go column of XT/XGb for next step.
__global__ __launch_bounds__(64) void ctxgo_k(const float* __restrict__ hen,
    const float* __restrict__ partial, const float* __restrict__ S,
    const float* __restrict__ pW, const float* __restrict__ pb,
    u16* __restrict__ XT, u16* __restrict__ XGb,
    float* __restrict__ outp, int tstep) {
  int bn = blockIdx.x; int r = threadIdx.x;
  __shared__ float a[12];
  __shared__ float l[12];
  if (r < 12) {
    float s = 0.f;
    for (int i = 0; i < 32; i++) s += partial[r * 32 + i];
    l[r] = s;
  }
  __syncthreads();
  if (r == 0) {
    float mx = l[0];
    for (int i = 1; i < 12; i++) mx = fmaxf(mx, l[i]);
    float se = 0.f; float e[12];
    for (int i = 0; i < 12; i++) { e[i] = expf(l[i] - mx); se += e[i]; }
    float inv = 1.f / se;
    for (int i = 0; i < 12; i++) a[i] = e[i] * inv;
  }
  __syncthreads();
  int b = bn >> 9, n = bn & 511;
  float ctx = 0.f;
#pragma unroll
  for (int t = 0; t < 12; t++)
    ctx = fmaf(hen[((size_t)(b * 12 + t) * 512 + n) * 64 + r], a[t], ctx);
  float part = ctx * pW[128 + r] + S[(size_t)bn * 128 + r] * pW[r]
             + S[(size_t)bn * 128 + 64 + r] * pW[64 + r];
#pragma unroll
  for (int off = 32; off > 0; off >>= 1) part += __shfl_down(part, off);
  if (r == 0) {
    float gv = part + pb[0];
    outp[(size_t)(b * 12 + tstep) * 512 + n] = gv;
    u16 bv = f2bu(gv);
    XT[((size_t)(b * 130)) * 512 + n] = bv;
    XGb[(size_t)bn * 800 + 0] = bv;
    XGb[(size_t)bn * 800 + 390] = bv;
  }
}

// ============================ host side ============================

static void fgemm(hipStream_t st, int epi, const float* A, const float* Bm,
                  const float* bias, float* C, int M, int N, int K, int ldb,
                  const float* aux0, float* aux1, float* aux2, float* aux3, float* aux4,
                  int i0, int i1, int i2) {
  FGemmArgs a{A, Bm, bias, C, M, N, K, ldb, aux0, aux1, aux2, aux3, aux4, i0, i1, i2};
  dim3 grid((N + 63) / 64, M / 64);
  switch (epi) {
    case 0: fgemm_k<0><<<grid, 256, 0, st>>>(a); break;
    case 1: fgemm_k<1><<<grid, 256, 0, st>>>(a); break;
    case 3: fgemm_k<3><<<grid, 256, 0, st>>>(a); break;
    case 4: fgemm_k<4><<<grid, 256, 0, st>>>(a); break;
  }
}

static void fgemm32(hipStream_t st, int epi, const float* A, const float* Bm,
                    const float* bias, float* C, int M, int N, int K, int ldb,
                    const float* aux0, float* aux1, float* aux2, float* aux3, float* aux4,
                    int i0, int i1, int i2) {
  FGemmArgs a{A, Bm, bias, C, M, N, K, ldb, aux0, aux1, aux2, aux3, aux4, i0, i1, i2};
  dim3 grid((N + 63) / 64, M / 32);
  switch (epi) {
    case 0: fgemm32_k<0><<<grid, 256, 0, st>>>(a); break;
    case 1: fgemm32_k<1><<<grid, 256, 0, st>>>(a); break;
    case 2: fgemm32_k<2><<<grid, 256, 0, st>>>(a); break;
    case 3: fgemm32_k<3><<<grid, 256, 0, st>>>(a); break;
    case 4: fgemm32_k<4><<<grid, 256, 0, st>>>(a); break;
    case 5: fgemm32_k<5><<<grid, 256, 0, st>>>(a); break;
  }
}

static void mm(hipStream_t st, int epi, const u16* A, const u16* BT,
               int M, int N, int K, const float* bias, float* C, u16* xg,
               const float* zr, float* state, float* hen, u16* xtw, u16* xgw,
               int i0, int i1, int i2) {
  MmArgs a{A, BT, M, N, K, bias, C, xg, zr, state, hen, xtw, xgw, i0, i1, i2};
  dim3 grid((N + 63) / 64, M / 64);
  switch (epi) {
    case EPI_SIG:  mm_k<EPI_SIG><<<grid, 256, 0, st>>>(a); break;
    case EPI_SCAT: mm_k<EPI_SCAT><<<grid, 256, 0, st>>>(a); break;
    case EPI_UPD:  mm_k<EPI_UPD><<<grid, 256, 0, st>>>(a); break;
  }
}

extern "C" void kernel_launch(void* const* d_in, const int* in_sizes, int n_in,
                              void* d_out, int out_size, void* d_ws, size_t ws_size,
                              hipStream_t stream) {
  (void)out_size; (void)ws_size; (void)n_in; (void)in_sizes;
  float* ws = (float*)d_ws;
  float* out = (float*)d_out;   // outputs are float32

  size_t off = 0;
  auto alloc = [&](size_t n) { size_t o = off; off += (n + 63) & ~(size_t)63; return ws + o; };

  const int isz[20] = {98304, 98304, 1280, 4096, 10240, 10240, 4096, 4096, 8192, 4096,
                       49920, 128, 24960, 64, 199680, 256, 99840, 128, 192, 1};
  float* fin[20];
  for (int i = 0; i < 20; i++) fin[i] = alloc((size_t)isz[i]);

  float* Gbig  = alloc((size_t)2048 * 512);
  float* tGbig = Gbig;  // lifetimes disjoint
  float* Mbuf  = alloc((size_t)512 * 512);
  float* ne1b  = alloc((size_t)512 * 64);
  float* ne2b  = alloc((size_t)512 * 64);
  float* neT   = alloc((size_t)64 * 512);
  float* X     = alloc((size_t)512 * 1088);
  float* XG    = alloc((size_t)8192 * 416);
  float* Wgp   = alloc((size_t)416 * 128);
  float* Wup   = alloc((size_t)416 * 64);
  float* zr    = alloc((size_t)8192 * 256);
  float* H     = alloc((size_t)8192 * 64);
  float* S     = alloc((size_t)8192 * 128);
  float* hen   = alloc((size_t)16 * 12 * 512 * 64);
  float* E     = alloc((size_t)16 * 12 * 512 * 64);
  float* Dflat = alloc((size_t)8192 * 64);
  float* partial = alloc((size_t)512);
  int* ind     = (int*)alloc((size_t)8192 * 20);
  int* dflag   = (int*)alloc((size_t)64);
  u16* Gb16 = (u16*)alloc((size_t)2048 * 512 / 2);
  u16* XT   = (u16*)alloc((size_t)2080 * 512 / 2);
  u16* XGb  = (u16*)alloc((size_t)8192 * 800 / 2);
  u16* WTdg = (u16*)alloc((size_t)256 * 800 / 2);
  u16* WTdu = (u16*)alloc((size_t)128 * 800 / 2);

  float* o_out   = out;
  float* o_hatt  = out + 98304;
  float* o_query = o_hatt + 524288;
  float* o_pos   = o_query + 524288;
  float* o_neg   = o_pos + 524288;
  float* o_att   = o_neg + 9961472;

  detect_k<<<1, 64, 0, stream>>>((const u16*)d_in[0], dflag);
  for (int i = 0; i < 20; i++)
    in2f_k<<<(isz[i] + 255) / 256, 256, 0, stream>>>(d_in[i], fin[i], isz[i], dflag);

  padw_k<<<(416 * 128 + 255) / 256, 256, 0, stream>>>(fin[10], Wgp, 390, 128, 416);
  padw_k<<<(416 * 64 + 255) / 256, 256, 0, stream>>>(fin[12], Wup, 390, 64, 416);
  w2bt_k<<<(256 * 800 + 255) / 256, 256, 0, stream>>>(fin[14], WTdg, 780, 256, 800);
  w2bt_k<<<(128 * 800 + 255) / 256, 256, 0, stream>>>(fin[16], WTdu, 780, 128, 800);

  zero_k<<<(512 * 1088 + 255) / 256, 256, 0, stream>>>(X, 512 * 1088);
  zero_k<<<(8192 * 416 + 255) / 256, 256, 0, stream>>>(XG, 8192 * 416);

  // --- encoder graph: Gbig = [g1; 2g1^2-I; g2; 2g2^2-I] (f32) ---
  {
    GemmArgs a1{fin[4], fin[2], ne1b, 512, 64, 20};
    gemm_s<<<dim3(1, 8), 256, 0, stream>>>(a1);
    GemmArgs a2{fin[5], fin[2], ne2b, 512, 64, 20};
    gemm_s<<<dim3(1, 8), 256, 0, stream>>>(a2);
  }
  transpose_k<<<(512 * 64 + 255) / 256, 256, 0, stream>>>(ne2b, neT, 512, 64);
  fgemm32(stream, EPI_RELU, ne1b, neT, nullptr, Mbuf, 512, 512, 64, 512,
          nullptr, nullptr, nullptr, nullptr, nullptr, 0, 0, 0);
  softmax512_k<<<512, 256, 0, stream>>>(Mbuf, Gbig, 0);
  softmax512_k<<<512, 256, 0, stream>>>(Mbuf, Gbig + (size_t)1024 * 512, 1);
  fgemm32(stream, EPI_CHEB, Gbig, Gbig, nullptr, Gbig + (size_t)512 * 512,
          512, 512, 512, 512, nullptr, nullptr, nullptr, nullptr, nullptr, 0, 0, 0);
  fgemm32(stream, EPI_CHEB, Gbig + (size_t)1024 * 512, Gbig + (size_t)1024 * 512, nullptr,
          Gbig + (size_t)1536 * 512, 512, 512, 512, 512,
          nullptr, nullptr, nullptr, nullptr, nullptr, 0, 0, 0);

  zero_k<<<(8192 * 64 + 255) / 256, 256, 0, stream>>>(H, 8192 * 64);

  // --- encoder: 12 graph-GRU steps (32-row-tile SCAT, fused epilogues) ---
  for (int t = 0; t < 12; t++) {
    putxe_k<<<32, 256, 0, stream>>>(fin[0] + t * 512, X, XG);
    fgemm32(stream, EPI_SCAT, Gbig, X, nullptr, nullptr, 2048, 1040, 512, 1088,
            nullptr, XG, nullptr, nullptr, nullptr, 65, 416, 0);
    fgemm32(stream, EPI_SIG, XG, Wgp, fin[11], zr, 8192, 128, 416, 128,
            H, nullptr, nullptr, X, XG, 0, 0, 0);
    fgemm32(stream, EPI_SCAT, Gbig, X, nullptr, nullptr, 2048, 1040, 512, 1088,
            nullptr, XG, nullptr, nullptr, nullptr, 65, 416, 0);
    fgemm32(stream, EPI_UPD, XG, Wup, fin[13], nullptr, 8192, 64, 416, 64,
            zr, H, hen, X, XG, 128, 64, t);
  }

  // --- memory attention (f32, index-exact) ---
  fgemm(stream, EPI_NONE, H, fin[3], nullptr, o_query, 8192, 64, 64, 64,
        nullptr, nullptr, nullptr, nullptr, nullptr, 0, 0, 0);
  attmem_k<<<32, 256, 0, stream>>>(o_query, fin[2], o_att, o_hatt, ind);
  gather_pn_k<<<(16 * 512 * 20 * 64 + 255) / 256, 256, 0, stream>>>(
      ind, fin[2], o_pos, o_neg);

  // --- E = h_en @ fc_e_W (before Gbig overwritten) ---
  fgemm(stream, EPI_NONE, hen, fin[9], nullptr, E, 98304, 64, 64, 64,
        nullptr, nullptr, nullptr, nullptr, nullptr, 0, 0, 0);

  // --- decoder graph from h_att[-1] (batch 15), f32 -> bf16 ---
  fgemm(stream, EPI_NONE, o_hatt + (size_t)15 * 512 * 64, fin[6], nullptr, ne1b,
        512, 64, 64, 64, nullptr, nullptr, nullptr, nullptr, nullptr, 0, 0, 0);
  fgemm(stream, EPI_NONE, o_hatt + (size_t)15 * 512 * 64, fin[7], nullptr, ne2b,
        512, 64, 64, 64, nullptr, nullptr, nullptr, nullptr, nullptr, 0, 0, 0);
  transpose_k<<<(512 * 64 + 255) / 256, 256, 0, stream>>>(ne2b, neT, 512, 64);
  fgemm32(stream, EPI_RELU, ne1b, neT, nullptr, Mbuf, 512, 512, 64, 512,
          nullptr, nullptr, nullptr, nullptr, nullptr, 0, 0, 0);
  softmax512_k<<<512, 256, 0, stream>>>(Mbuf, tGbig, 0);
  softmax512_k<<<512, 256, 0, stream>>>(Mbuf, tGbig + (size_t)1024 * 512, 1);
  fgemm32(stream, EPI_CHEB, tGbig, tGbig, nullptr, tGbig + (size_t)512 * 512,
          512, 512, 512, 512, nullptr, nullptr, nullptr, nullptr, nullptr, 0, 0, 0);
  fgemm32(stream, EPI_CHEB, tGbig + (size_t)1024 * 512, tGbig + (size_t)1024 * 512, nullptr,
          tGbig + (size_t)1536 * 512, 512, 512, 512, 512,
          nullptr, nullptr, nullptr, nullptr, nullptr, 0, 0, 0);
  f2b_k<<<(2048 * 512 + 255) / 256, 256, 0, stream>>>(tGbig, Gb16, 2048 * 512);

  zeroi_k<<<(8192 * 800 / 2 + 255) / 256, 256, 0, stream>>>((int*)XGb, 8192 * 800 / 2);
  sinit_k<<<(8192 * 128 + 255) / 256, 256, 0, stream>>>(H, o_hatt, S, XT, XGb);

  // --- decoder: 12 graph-GRU steps (fused epilogues) ---
  for (int t = 0; t < 12; t++) {
    putxd_k<<<32, 256, 0, stream>>>(fin[1] + t * 512, XT, XGb);
    mm(stream, EPI_SCAT, Gb16, XT, 2048, 2080, 512, nullptr, nullptr, XGb,
       nullptr, nullptr, nullptr, nullptr, nullptr, 130, 800, 0);
    mm(stream, EPI_SIG, XGb, WTdg, 8192, 256, 800, fin[15], zr, nullptr,
       nullptr, S, nullptr, XT, XGb, 0, 0, 0);
    mm(stream, EPI_SCAT, Gb16, XT, 2048, 2080, 512, nullptr, nullptr, XGb,
       nullptr, nullptr, nullptr, nullptr, nullptr, 130, 800, 0);
    mm(stream, EPI_UPD, XGb, WTdu, 8192, 128, 800, fin[17], nullptr, nullptr,
       zr, S, nullptr, XT, XGb, 256, 128, 0);
    fgemm32(stream, EPI_NONE, S, fin[8], nullptr, Dflat, 8192, 64, 128, 64,
            nullptr, nullptr, nullptr, nullptr, nullptr, 0, 0, 0);
    att_dot_k<<<dim3(32, 12), 256, 0, stream>>>(E, Dflat, partial);
    ctxgo_k<<<8192, 64, 0, stream>>>(hen, partial, S, fin[18], fin[19],
                                     XT, XGb, o_out, t);
  }
}

// Round 16
// 3357.726 us; speedup vs baseline: 1.0647x; 1.0647x over previous
//
#include <hip/hip_runtime.h>
#include <hip/hip_bf16.h>
#include <math.h>

typedef __hip_bfloat16 bf16;
typedef __attribute__((ext_vector_type(8))) short short8;
typedef __attribute__((ext_vector_type(4))) float f32x4;
typedef unsigned short u16;

__device__ inline u16 f2bu(float f) {            // f32 -> bf16 bits, RNE
  unsigned u = __builtin_bit_cast(unsigned, f);
  u += 0x7fffu + ((u >> 16) & 1u);
  return (u16)(u >> 16);
}

__global__ void zero_k(float* __restrict__ p, int n) {
  int i = blockIdx.x * 256 + threadIdx.x;
  if (i < n) p[i] = 0.f;
}

__global__ void zeroi_k(int* __restrict__ p, int n) {
  int i = blockIdx.x * 256 + threadIdx.x;
  if (i < n) p[i] = 0;
}

__global__ void transpose_k(const float* __restrict__ in, float* __restrict__ out,
                            int rows, int cols) {
  int i = blockIdx.x * 256 + threadIdx.x;
  if (i >= rows * cols) return;
  int c = i % cols, r = i / cols;
  out[(size_t)c * rows + r] = in[i];
}

// f32 -> bf16 bits
__global__ void f2b_k(const float* __restrict__ in, u16* __restrict__ out, int n) {
  int i = blockIdx.x * 256 + threadIdx.x;
  if (i < n) out[i] = f2bu(in[i]);
}

// W[K][N] f32 -> Wp[Kpad][N] f32, zero pad
__global__ void padw_k(const float* __restrict__ W, float* __restrict__ Wp,
                       int K, int N, int Kpad) {
  int i = blockIdx.x * 256 + threadIdx.x;
  if (i >= Kpad * N) return;
  int n = i % N, k = i / N;
  Wp[i] = (k < K) ? W[(size_t)k * N + n] : 0.f;
}

// W[KT][Nw] f32 -> WT[Nw][KTpad] bf16 (pad zero)
__global__ void w2bt_k(const float* __restrict__ W, u16* __restrict__ WT,
                       int KT, int Nw, int KTpad) {
  int i = blockIdx.x * 256 + threadIdx.x;
  if (i >= Nw * KTpad) return;
  int kp = i % KTpad, n = i / KTpad;
  WT[i] = (kp < KT) ? f2bu(W[(size_t)kp * Nw + n]) : (u16)0;
}

enum { EPI_NONE = 0, EPI_RELU = 1, EPI_SIG = 2, EPI_CHEB = 3, EPI_SCAT = 4, EPI_UPD = 5 };

// ============================ slow guarded f32 GEMM (K=20 cases) ============================
struct GemmArgs {
  const float* A; const float* Bm; float* C;
  int M, N, K;
};
__global__ __launch_bounds__(256) void gemm_s(GemmArgs g) {
  __shared__ float As[16][65];
  __shared__ float Bs[16][65];
  const int tid = threadIdx.x;
  const int tx = tid & 15, ty = tid >> 4;
  const int bm = blockIdx.y * 64, bn = blockIdx.x * 64;
  float acc[4][4] = {{0.f}};
  for (int k0 = 0; k0 < g.K; k0 += 16) {
#pragma unroll
    for (int i = 0; i < 4; i++) {
      int idx = i * 256 + tid; int c = idx & 15, r = idx >> 4;
      int mm = bm + r, kk = k0 + c;
      As[c][r] = (mm < g.M && kk < g.K) ? g.A[(size_t)mm * g.K + kk] : 0.f;
    }
#pragma unroll
    for (int i = 0; i < 4; i++) {
      int idx = i * 256 + tid; int c = idx & 63, r = idx >> 6;
      int kk = k0 + r, nn = bn + c;
      Bs[r][c] = (kk < g.K && nn < g.N) ? g.Bm[(size_t)kk * g.N + nn] : 0.f;
    }
    __syncthreads();
#pragma unroll
    for (int kk = 0; kk < 16; kk++) {
      float a[4], b[4];
#pragma unroll
      for (int i = 0; i < 4; i++) a[i] = As[kk][ty * 4 + i];
#pragma unroll
      for (int j = 0; j < 4; j++) b[j] = Bs[kk][tx * 4 + j];
#pragma unroll
      for (int i = 0; i < 4; i++)
#pragma unroll
        for (int j = 0; j < 4; j++) acc[i][j] = fmaf(a[i], b[j], acc[i][j]);
    }
    __syncthreads();
  }
#pragma unroll
  for (int i = 0; i < 4; i++) {
    int m = bm + ty * 4 + i;
    if (m >= g.M) continue;
#pragma unroll
    for (int j = 0; j < 4; j++) {
      int n = bn + tx * 4 + j;
      if (n >= g.N) continue;
      g.C[(size_t)m * g.N + n] = acc[i][j];
    }
  }
}

// ============================ fast f32 GEMM (dbuf, BK=16, K%16==0, M%64==0) ==========
// Best-measured SCAT config (rounds 11-12: 49.9 us). Per-output k ascending.
struct FGemmArgs {
  const float* A; const float* Bm; const float* bias; float* C;
  int M, N, K, ldb;
  const float* aux0;  // zr (UPD) | H read (SIG enc)
  float* aux1;        // XG (SCAT) | H state (UPD)
  float* aux2;        // h_en base (UPD)
  float* aux3;        // X write (SIG/UPD enc fusion)
  float* aux4;        // XG write (SIG/UPD enc fusion)
  int i0, i1, i2;     // SCAT: C,ldXG | UPD: zr_ld, hdim, t
};

template<int EPI>
__global__ __launch_bounds__(256) void fgemm_k(FGemmArgs g) {
  __shared__ __align__(16) float As[2][16][68];
  __shared__ __align__(16) float Bs[2][16][68];
  const int tid = threadIdx.x;
  const int tx = tid & 15, ty = tid >> 4;
  const int bm = blockIdx.y * 64, bn = blockIdx.x * 64;
  const int ar = tid >> 2, ac = (tid & 3) * 4;
  const int br = tid >> 4, bc = (tid & 15) * 4;
  float acc[4][4] = {{0.f}};

  float4 av = *(const float4*)(g.A + (size_t)(bm + ar) * g.K + ac);
  float4 bv = *(const float4*)(g.Bm + (size_t)br * g.ldb + bn + bc);
  As[0][ac + 0][ar] = av.x; As[0][ac + 1][ar] = av.y;
  As[0][ac + 2][ar] = av.z; As[0][ac + 3][ar] = av.w;
  *(float4*)&Bs[0][br][bc] = bv;
  __syncthreads();

  int cur = 0;
  for (int k0 = 0; k0 < g.K; k0 += 16) {
    const bool has_next = (k0 + 16 < g.K);
    if (has_next) {
      av = *(const float4*)(g.A + (size_t)(bm + ar) * g.K + k0 + 16 + ac);
      bv = *(const float4*)(g.Bm + (size_t)(k0 + 16 + br) * g.ldb + bn + bc);
    }
#pragma unroll
    for (int kk = 0; kk < 16; kk++) {
      float4 a4 = *(const float4*)&As[cur][kk][ty * 4];
      float4 b4 = *(const float4*)&Bs[cur][kk][tx * 4];
      float a[4] = {a4.x, a4.y, a4.z, a4.w};
      float b[4] = {b4.x, b4.y, b4.z, b4.w};
#pragma unroll
      for (int i = 0; i < 4; i++)
#pragma unroll
        for (int j = 0; j < 4; j++) acc[i][j] = fmaf(a[i], b[j], acc[i][j]);
    }
    if (has_next) {
      int nxt = cur ^ 1;
      As[nxt][ac + 0][ar] = av.x; As[nxt][ac + 1][ar] = av.y;
      As[nxt][ac + 2][ar] = av.z; As[nxt][ac + 3][ar] = av.w;
      *(float4*)&Bs[nxt][br][bc] = bv;
      __syncthreads();
      cur = nxt;
    }
  }
#pragma unroll
  for (int i = 0; i < 4; i++) {
    int m = bm + ty * 4 + i;
#pragma unroll
    for (int j = 0; j < 4; j++) {
      int n = bn + tx * 4 + j;
      if (n >= g.N) continue;
      float v = acc[i][j];
      if (EPI == EPI_NONE) {
        g.C[(size_t)m * g.N + n] = v;
      } else if (EPI == EPI_RELU) {
        g.C[(size_t)m * g.N + n] = fmaxf(v, 0.f);
      } else if (EPI == EPI_CHEB) {
        g.C[(size_t)m * g.N + n] = 2.f * v - (m == n ? 1.f : 0.f);
      } else if (EPI == EPI_SCAT) {
        int bb = n / g.i0, cc = n % g.i0;
        int km = m >> 9;
        int kmap = km + 1 + (km >= 2 ? 1 : 0);
        int node = m & 511;
        g.aux1[((size_t)bb * 512 + node) * g.i1 + (size_t)kmap * g.i0 + cc] = v;
      }
    }
  }
}

// ============================ TM=32 f32 GEMM (dbuf BK=16) =============
// For N=64/128 shapes + setup GEMMs. Fused enc SIG/UPD epilogues.
template<int EPI>
__global__ __launch_bounds__(256) void fgemm32_k(FGemmArgs g) {
  __shared__ __align__(16) float As[2][16][40];
  __shared__ __align__(16) float Bs[2][16][68];
  const int tid = threadIdx.x;
  const int tx = tid & 15, ty = tid >> 4;
  const int bm = blockIdx.y * 32, bn = blockIdx.x * 64;
  const int ar = tid >> 2, ac = (tid & 3) * 4;
  const int br = tid >> 4, bc = (tid & 15) * 4;
  float acc[2][4] = {{0.f}};

  float4 av, bv;
  if (ar < 32) av = *(const float4*)(g.A + (size_t)(bm + ar) * g.K + ac);
  bv = *(const float4*)(g.Bm + (size_t)br * g.ldb + bn + bc);
  if (ar < 32) {
    As[0][ac + 0][ar] = av.x; As[0][ac + 1][ar] = av.y;
    As[0][ac + 2][ar] = av.z; As[0][ac + 3][ar] = av.w;
  }
  *(float4*)&Bs[0][br][bc] = bv;
  __syncthreads();

  int cur = 0;
  for (int k0 = 0; k0 < g.K; k0 += 16) {
    const bool has_next = (k0 + 16 < g.K);
    if (has_next) {
      if (ar < 32) av = *(const float4*)(g.A + (size_t)(bm + ar) * g.K + k0 + 16 + ac);
      bv = *(const float4*)(g.Bm + (size_t)(k0 + 16 + br) * g.ldb + bn + bc);
    }
#pragma unroll
    for (int kk = 0; kk < 16; kk++) {
      float a0 = As[cur][kk][ty * 2 + 0];
      float a1 = As[cur][kk][ty * 2 + 1];
      float4 b4 = *(const float4*)&Bs[cur][kk][tx * 4];
      float b[4] = {b4.x, b4.y, b4.z, b4.w};
#pragma unroll
      for (int j = 0; j < 4; j++) {
        acc[0][j] = fmaf(a0, b[j], acc[0][j]);
        acc[1][j] = fmaf(a1, b[j], acc[1][j]);
      }
    }
    if (has_next) {
      int nxt = cur ^ 1;
      if (ar < 32) {
        As[nxt][ac + 0][ar] = av.x; As[nxt][ac + 1][ar] = av.y;
        As[nxt][ac + 2][ar] = av.z; As[nxt][ac + 3][ar] = av.w;
      }
      *(float4*)&Bs[nxt][br][bc] = bv;
      __syncthreads();
      cur = nxt;
    }
  }
#pragma unroll
  for (int i = 0; i < 2; i++) {
    int m = bm + ty * 2 + i;
    int node = m & 511, bb = m >> 9;
#pragma unroll
    for (int j = 0; j < 4; j++) {
      int n = bn + tx * 4 + j;
      if (n >= g.N) continue;
      float v = acc[i][j];
      if (EPI == EPI_NONE) {
        g.C[(size_t)m * g.N + n] = v;
      } else if (EPI == EPI_RELU) {
        g.C[(size_t)m * g.N + n] = fmaxf(v, 0.f);
      } else if (EPI == EPI_CHEB) {
        g.C[(size_t)m * g.N + n] = 2.f * v - (m == n ? 1.f : 0.f);
      } else if (EPI == EPI_SIG) {
        v += g.bias[n];
        float sg = 1.f / (1.f + expf(-v));
        g.C[(size_t)m * g.N + n] = sg;
        if (n < 64) {
          float zh = sg * g.aux0[(size_t)m * 64 + n];   // aux0 = H
          g.aux3[(size_t)node * 1088 + bb * 65 + 1 + n] = zh;
          g.aux4[(size_t)m * 416 + 1 + n] = zh;
          g.aux4[(size_t)m * 416 + 196 + n] = zh;
        }
      } else if (EPI == EPI_UPD) {
        v = tanhf(v + g.bias[n]);
        float r = g.aux0[(size_t)m * g.i0 + g.i1 + n];
        float h = r * g.aux1[(size_t)m * g.i1 + n] + (1.f - r) * v;
        g.aux1[(size_t)m * g.i1 + n] = h;
        if (g.aux2)
          g.aux2[(((size_t)bb * 12 + g.i2) * 512 + node) * 64 + n] = h;
        g.aux3[(size_t)node * 1088 + bb * 65 + 1 + n] = h;
        g.aux4[(size_t)m * 416 + 1 + n] = h;
        g.aux4[(size_t)m * 416 + 196 + n] = h;
      }
    }
  }
}

// ============================ plain bf16 MFMA GEMM, dbuf (decoder) ============================
struct MmArgs {
  const u16* A; const u16* BT; int M, N, K;
  const float* bias; float* C;                 // SIG: zr out
  u16* xg;                                     // SCAT dest
  const float* zr; float* state; float* hen;   // UPD
  u16* xtw; u16* xgw;                          // fused XT/XGb writes (SIG/UPD)
  int i0, i1, i2;
};

template<int EPI>
__global__ __launch_bounds__(256) void mm_k(MmArgs g) {
  __shared__ __align__(16) u16 Als[2][64][40];
  __shared__ __align__(16) u16 Bls[2][64][40];
  const int tid = threadIdx.x;
  const int w = tid >> 6, lane = tid & 63;
  const int l15 = lane & 15, lk = lane >> 4;
  const int m0 = blockIdx.y * 64, n0 = blockIdx.x * 64;
  const int srow = tid >> 2, schunk = tid & 3;
  f32x4 acc[4];
#pragma unroll
  for (int j = 0; j < 4; j++) acc[j] = (f32x4){0.f, 0.f, 0.f, 0.f};

  short8 a8 = *(const short8*)(g.A + (size_t)(m0 + srow) * g.K + schunk * 8);
  short8 b8 = (short8){0,0,0,0,0,0,0,0};
  if (n0 + srow < g.N)
    b8 = *(const short8*)(g.BT + (size_t)(n0 + srow) * g.K + schunk * 8);
  *(short8*)&Als[0][srow][schunk * 8] = a8;
  *(short8*)&Bls[0][srow][schunk * 8] = b8;
  __syncthreads();

  int cur = 0;
  for (int k0 = 0; k0 < g.K; k0 += 32) {
    const bool has_next = (k0 + 32 < g.K);
    if (has_next) {
      a8 = *(const short8*)(g.A + (size_t)(m0 + srow) * g.K + k0 + 32 + schunk * 8);
      b8 = (short8){0,0,0,0,0,0,0,0};
      if (n0 + srow < g.N)
        b8 = *(const short8*)(g.BT + (size_t)(n0 + srow) * g.K + k0 + 32 + schunk * 8);
    }
    short8 af = *(const short8*)&Als[cur][w * 16 + l15][lk * 8];
#pragma unroll
    for (int j = 0; j < 4; j++) {
      short8 bf = *(const short8*)&Bls[cur][j * 16 + l15][lk * 8];
      acc[j] = __builtin_amdgcn_mfma_f32_16x16x32_bf16(af, bf, acc[j], 0, 0, 0);
    }
    if (has_next) {
      int nxt = cur ^ 1;
      *(short8*)&Als[nxt][srow][schunk * 8] = a8;
      *(short8*)&Bls[nxt][srow][schunk * 8] = b8;
      __syncthreads();
      cur = nxt;
    }
  }

#pragma unroll
  for (int j = 0; j < 4; j++) {
    int col = n0 + j * 16 + l15;
    if (col >= g.N) continue;
#pragma unroll
    for (int r = 0; r < 4; r++) {
      int row = m0 + w * 16 + lk * 4 + r;
      int node = row & 511, bb = row >> 9;
      float v = acc[j][r];
      if (EPI == EPI_SCAT) {
        int b2 = col / g.i0, cc = col % g.i0;
        int km = row >> 9;
        int kmap = km + 1 + (km >= 2 ? 1 : 0);
        g.xg[((size_t)b2 * 512 + node) * g.i1 + (size_t)kmap * g.i0 + cc] = f2bu(v);
      } else if (EPI == EPI_SIG) {
        v += g.bias[col];
        float sg = 1.f / (1.f + expf(-v));
        g.C[(size_t)row * g.N + col] = sg;
        if (col < 128) {
          float zh = sg * g.state[(size_t)row * 128 + col];
          u16 bv = f2bu(zh);
          g.xtw[((size_t)(bb * 130 + 2 + col)) * 512 + node] = bv;
          g.xgw[(size_t)row * 800 + 2 + col] = bv;
          g.xgw[(size_t)row * 800 + 392 + col] = bv;
        }
      } else if (EPI == EPI_UPD) {
        v = tanhf(v + g.bias[col]);
        float rr = g.zr[(size_t)row * g.i0 + g.i1 + col];
        float h = rr * g.state[(size_t)row * g.i1 + col] + (1.f - rr) * v;
        g.state[(size_t)row * g.i1 + col] = h;
        u16 bv = f2bu(h);
        g.xtw[((size_t)(bb * 130 + 2 + col)) * 512 + node] = bv;
        g.xgw[(size_t)row * 800 + 2 + col] = bv;
        g.xgw[(size_t)row * 800 + 392 + col] = bv;
      }
    }
  }
}

// ============================ model-specific kernels ============================

__global__ void putxe_k(const float* __restrict__ x1, float* __restrict__ X,
                        float* __restrict__ XG) {
  int bn = blockIdx.x * 256 + threadIdx.x;
  if (bn >= 8192) return;
  int n = bn & 511, b = bn >> 9;
  float v = x1[(size_t)b * 6144 + n];
  X[(size_t)n * 1088 + b * 65] = v;
  XG[(size_t)bn * 416 + 0] = v;
  XG[(size_t)bn * 416 + 195] = v;
}

__global__ void putxd_k(const float* __restrict__ yc, u16* __restrict__ XT,
                        u16* __restrict__ XGb) {
  int bn = blockIdx.x * 256 + threadIdx.x;
  if (bn >= 8192) return;
  int n = bn & 511, b = bn >> 9;
  u16 bv = f2bu(yc[(size_t)b * 6144 + n]);
  XT[((size_t)(b * 130 + 1)) * 512 + n] = bv;
  XGb[(size_t)bn * 800 + 1] = bv;
  XGb[(size_t)bn * 800 + 391] = bv;
}

__global__ __launch_bounds__(256) void softmax512_k(const float* __restrict__ Min,
                                                    float* __restrict__ out, int colMajor) {
  int row = blockIdx.x;
  __shared__ float buf[512];
  __shared__ float red[256];
  int tid = threadIdx.x;
  for (int i = tid; i < 512; i += 256)
    buf[i] = colMajor ? Min[(size_t)i * 512 + row] : Min[(size_t)row * 512 + i];
  __syncthreads();
  float mx = -1e30f;
  for (int i = tid; i < 512; i += 256) mx = fmaxf(mx, buf[i]);
  red[tid] = mx; __syncthreads();
  for (int w = 128; w > 0; w >>= 1) { if (tid < w) red[tid] = fmaxf(red[tid], red[tid + w]); __syncthreads(); }
  mx = red[0]; __syncthreads();
  float s = 0.f;
  for (int i = tid; i < 512; i += 256) { float e = expf(buf[i] - mx); buf[i] = e; s += e; }
  red[tid] = s; __syncthreads();
  for (int w = 128; w > 0; w >>= 1) { if (tid < w) red[tid] += red[tid + w]; __syncthreads(); }
  float inv = 1.f / red[0];
  for (int i = tid; i < 512; i += 256) out[(size_t)row * 512 + i] = buf[i] * inv;
}

__global__ __launch_bounds__(256) void attmem_k(const float* __restrict__ query,
    const float* __restrict__ Mem, float* __restrict__ att_out,
    float* __restrict__ hatt, int* __restrict__ ind) {
  __shared__ float sm[20 * 64];
  for (int i = threadIdx.x; i < 20 * 64; i += 256) sm[i] = Mem[i];
  __syncthreads();
  int bn = blockIdx.x * 256 + threadIdx.x;
  if (bn >= 16 * 512) return;
  float q[64];
#pragma unroll
  for (int d = 0; d < 64; d++) q[d] = query[(size_t)bn * 64 + d];
  float lg[20];
  float mx = -1e30f;
#pragma unroll
  for (int m = 0; m < 20; m++) {
    float s = 0.f;
#pragma unroll
    for (int d = 0; d < 64; d++) s = fmaf(q[d], sm[m * 64 + d], s);
    lg[m] = s; mx = fmaxf(mx, s);
  }
  float se = 0.f;
#pragma unroll
  for (int m = 0; m < 20; m++) { lg[m] = expf(lg[m] - mx); se += lg[m]; }
  float inv = 1.f / se;
#pragma unroll
  for (int m = 0; m < 20; m++) {
    lg[m] *= inv;
    att_out[(size_t)bn * 20 + m] = lg[m];
  }
#pragma unroll
  for (int d = 0; d < 64; d++) {
    float s = 0.f;
#pragma unroll
    for (int m = 0; m < 20; m++) s = fmaf(lg[m], sm[m * 64 + d], s);
    hatt[(size_t)bn * 64 + d] = s;
  }
  unsigned used = 0;
  for (int s = 0; s < 20; s++) {
    float bv = -1e30f; int bi = 0;
#pragma unroll
    for (int m = 0; m < 20; m++) {
      bool better = (!((used >> m) & 1u)) && (lg[m] > bv);
      if (better) { bv = lg[m]; bi = m; }
    }
    used |= (1u << bi);
    ind[(size_t)bn * 20 + s] = bi;
  }
}

__global__ void gather_pn_k(const int* __restrict__ ind, const float* __restrict__ Memf,
                            float* __restrict__ pos, float* __restrict__ neg) {
  size_t i = (size_t)blockIdx.x * 256 + threadIdx.x;
  if (i >= (size_t)16 * 512 * 20 * 64) return;
  int d = (int)(i & 63); size_t r = i >> 6;
  int s = (int)(r % 20); size_t bn = r / 20;
  int m = ind[bn * 20 + s];
  float v = Memf[m * 64 + d];
  if (s == 0) pos[bn * 64 + d] = v;
  else neg[(bn * 19 + (size_t)(s - 1)) * 64 + d] = v;
}

__global__ void sinit_k(const float* __restrict__ H, const float* __restrict__ hatt,
                        float* __restrict__ S, u16* __restrict__ XT,
                        u16* __restrict__ XGb) {
  int i = blockIdx.x * 256 + threadIdx.x;
  if (i >= 8192 * 128) return;
  int c = i & 127; int bn = i >> 7;
  int n = bn & 511, b = bn >> 9;
  float v = (c < 64) ? H[(size_t)bn * 64 + c] : hatt[(size_t)bn * 64 + (c - 64)];
  S[i] = v;
  u16 bv = f2bu(v);
  XT[((size_t)(b * 130 + 2 + c)) * 512 + n] = bv;
  XGb[(size_t)bn * 800 + 2 + c] = bv;
  XGb[(size_t)bn * 800 + 392 + c] = bv;
  if (c == 0) {
    XT[((size_t)(b * 130)) * 512 + n] = 0;
  }
}

__global__ __launch_bounds__(256) void att_dot_k(const float* __restrict__ E,
    const float* __restrict__ D, float* __restrict__ partial) {
  int t = blockIdx.y, ch = blockIdx.x;
  const float* e = E + (size_t)t * 524288 + (size_t)ch * 16384;
  const float* d = D + (size_t)ch * 16384;
  float s = 0.f;
  for (int i = threadIdx.x; i < 16384; i += 256) s = fmaf(e[i], d[i], s);
  __shared__ float red[256];
  red[threadIdx.x] = s; __syncthreads();
  for (int w = 128; w > 0; w >>= 1) {
    if (threadIdx.x < w) red[threadIdx.x] += red[threadIdx.x + w];
    __syncthreads();
  }
  if (threadIdx.x == 0) partial[t * 32 + ch] = red[0];
}

// context + projection + internal softmax(att); writes output AND go column.
__global__ __launch_bounds__(64) void ctxgo_k(const float* __restrict__ hen,
    const float* __restrict__ partial, const float* __restrict__ S,
    const float* __restrict__ pW, const float* __restrict__ pb,
    u16* __restrict__ XT, u16* __restrict__ XGb,
    float* __restrict__ outp, int tstep) {
  int bn = blockIdx.x; int r = threadIdx.x;
  __shared__ float a[12];
  __shared__ float l[12];
  if (r < 12) {
    float s = 0.f;
    for (int i = 0; i < 32; i++) s += partial[r * 32 + i];
    l[r] = s;
  }
  __syncthreads();
  if (r == 0) {
    float mx = l[0];
    for (int i = 1; i < 12; i++) mx = fmaxf(mx, l[i]);
    float se = 0.f; float e[12];
    for (int i = 0; i < 12; i++) { e[i] = expf(l[i] - mx); se += e[i]; }
    float inv = 1.f / se;
    for (int i = 0; i < 12; i++) a[i] = e[i] * inv;
  }
  __syncthreads();
  int b = bn >> 9, n = bn & 511;
  float ctx = 0.f;
#pragma unroll
  for (int t = 0; t < 12; t++)
    ctx = fmaf(hen[((size_t)(b * 12 + t) * 512 + n) * 64 + r], a[t], ctx);
  float part = ctx * pW[128 + r] + S[(size_t)bn * 128 + r] * pW[r]
             + S[(size_t)bn * 128 + 64 + r] * pW[64 + r];
#pragma unroll
  for (int off = 32; off > 0; off >>= 1) part += __shfl_down(part, off);
  if (r == 0) {
    float gv = part + pb[0];
    outp[(size_t)(b * 12 + tstep) * 512 + n] = gv;
    u16 bv = f2bu(gv);
    XT[((size_t)(b * 130)) * 512 + n] = bv;
    XGb[(size_t)bn * 800 + 0] = bv;
    XGb[(size_t)bn * 800 + 390] = bv;
  }
}

// ============================ host side ============================

static void fgemm(hipStream_t st, int epi, const float* A, const float* Bm,
                  const float* bias, float* C, int M, int N, int K, int ldb,
                  const float* aux0, float* aux1, float* aux2, float* aux3, float* aux4,
                  int i0, int i1, int i2) {
  FGemmArgs a{A, Bm, bias, C, M, N, K, ldb, aux0, aux1, aux2, aux3, aux4, i0, i1, i2};
  dim3 grid((N + 63) / 64, M / 64);
  switch (epi) {
    case 0: fgemm_k<0><<<grid, 256, 0, st>>>(a); break;
    case 1: fgemm_k<1><<<grid, 256, 0, st>>>(a); break;
    case 3: fgemm_k<3><<<grid, 256, 0, st>>>(a); break;
    case 4: fgemm_k<4><<<grid, 256, 0, st>>>(a); break;
  }
}

static void fgemm32(hipStream_t st, int epi, const float* A, const float* Bm,
                    const float* bias, float* C, int M, int N, int K, int ldb,
                    const float* aux0, float* aux1, float* aux2, float* aux3, float* aux4,
                    int i0, int i1, int i2) {
  FGemmArgs a{A, Bm, bias, C, M, N, K, ldb, aux0, aux1, aux2, aux3, aux4, i0, i1, i2};
  dim3 grid((N + 63) / 64, M / 32);
  switch (epi) {
    case 0: fgemm32_k<0><<<grid, 256, 0, st>>>(a); break;
    case 1: fgemm32_k<1><<<grid, 256, 0, st>>>(a); break;
    case 2: fgemm32_k<2><<<grid, 256, 0, st>>>(a); break;
    case 3: fgemm32_k<3><<<grid, 256, 0, st>>>(a); break;
    case 5: fgemm32_k<5><<<grid, 256, 0, st>>>(a); break;
  }
}

static void mm(hipStream_t st, int epi, const u16* A, const u16* BT,
               int M, int N, int K, const float* bias, float* C, u16* xg,
               const float* zr, float* state, float* hen, u16* xtw, u16* xgw,
               int i0, int i1, int i2) {
  MmArgs a{A, BT, M, N, K, bias, C, xg, zr, state, hen, xtw, xgw, i0, i1, i2};
  dim3 grid((N + 63) / 64, M / 64);
  switch (epi) {
    case EPI_SIG:  mm_k<EPI_SIG><<<grid, 256, 0, st>>>(a); break;
    case EPI_SCAT: mm_k<EPI_SCAT><<<grid, 256, 0, st>>>(a); break;
    case EPI_UPD:  mm_k<EPI_UPD><<<grid, 256, 0, st>>>(a); break;
  }
}

extern "C" void kernel_launch(void* const* d_in, const int* in_sizes, int n_in,
                              void* d_out, int out_size, void* d_ws, size_t ws_size,
                              hipStream_t stream) {
  (void)out_size; (void)ws_size; (void)n_in; (void)in_sizes;
  float* ws = (float*)d_ws;
  float* out = (float*)d_out;   // outputs are float32

  // inputs are float32 (established rounds 1-15); read d_in directly
  const float* in_x    = (const float*)d_in[0];
  const float* in_ycov = (const float*)d_in[1];
  const float* in_mem  = (const float*)d_in[2];
  const float* in_wq   = (const float*)d_in[3];
  const float* in_we1  = (const float*)d_in[4];
  const float* in_we2  = (const float*)d_in[5];
  const float* in_twe1 = (const float*)d_in[6];
  const float* in_twe2 = (const float*)d_in[7];
  const float* in_fcd  = (const float*)d_in[8];
  const float* in_fce  = (const float*)d_in[9];
  const float* in_egW  = (const float*)d_in[10];
  const float* in_egb  = (const float*)d_in[11];
  const float* in_euW  = (const float*)d_in[12];
  const float* in_eub  = (const float*)d_in[13];
  const float* in_dgW  = (const float*)d_in[14];
  const float* in_dgb  = (const float*)d_in[15];
  const float* in_duW  = (const float*)d_in[16];
  const float* in_dub  = (const float*)d_in[17];
  const float* in_pW   = (const float*)d_in[18];
  const float* in_pb   = (const float*)d_in[19];

  size_t off = 0;
  auto alloc = [&](size_t n) { size_t o = off; off += (n + 63) & ~(size_t)63; return ws + o; };

  float* Gbig  = alloc((size_t)2048 * 512);
  float* tGbig = Gbig;  // lifetimes disjoint
  float* Mbuf  = alloc((size_t)512 * 512);
  float* ne1b  = alloc((size_t)512 * 64);
  float* ne2b  = alloc((size_t)512 * 64);
  float* neT   = alloc((size_t)64 * 512);
  float* X     = alloc((size_t)512 * 1088);
  float* XG    = alloc((size_t)8192 * 416);
  float* Wgp   = alloc((size_t)416 * 128);
  float* Wup   = alloc((size_t)416 * 64);
  float* zr    = alloc((size_t)8192 * 256);
  float* H     = alloc((size_t)8192 * 64);
  float* S     = alloc((size_t)8192 * 128);
  float* hen   = alloc((size_t)16 * 12 * 512 * 64);
  float* E     = alloc((size_t)16 * 12 * 512 * 64);
  float* Dflat = alloc((size_t)8192 * 64);
  float* partial = alloc((size_t)512);
  int* ind     = (int*)alloc((size_t)8192 * 20);
  u16* Gb16 = (u16*)alloc((size_t)2048 * 512 / 2);
  u16* XT   = (u16*)alloc((size_t)2080 * 512 / 2);
  u16* XGb  = (u16*)alloc((size_t)8192 * 800 / 2);
  u16* WTdg = (u16*)alloc((size_t)256 * 800 / 2);
  u16* WTdu = (u16*)alloc((size_t)128 * 800 / 2);

  float* o_out   = out;
  float* o_hatt  = out + 98304;
  float* o_query = o_hatt + 524288;
  float* o_pos   = o_query + 524288;
  float* o_neg   = o_pos + 524288;
  float* o_att   = o_neg + 9961472;

  padw_k<<<(416 * 128 + 255) / 256, 256, 0, stream>>>(in_egW, Wgp, 390, 128, 416);
  padw_k<<<(416 * 64 + 255) / 256, 256, 0, stream>>>(in_euW, Wup, 390, 64, 416);
  w2bt_k<<<(256 * 800 + 255) / 256, 256, 0, stream>>>(in_dgW, WTdg, 780, 256, 800);
  w2bt_k<<<(128 * 800 + 255) / 256, 256, 0, stream>>>(in_duW, WTdu, 780, 128, 800);

  zero_k<<<(512 * 1088 + 255) / 256, 256, 0, stream>>>(X, 512 * 1088);
  zero_k<<<(8192 * 416 + 255) / 256, 256, 0, stream>>>(XG, 8192 * 416);

  // --- encoder graph: Gbig = [g1; 2g1^2-I; g2; 2g2^2-I] (f32) ---
  {
    GemmArgs a1{in_we1, in_mem, ne1b, 512, 64, 20};
    gemm_s<<<dim3(1, 8), 256, 0, stream>>>(a1);
    GemmArgs a2{in_we2, in_mem, ne2b, 512, 64, 20};
    gemm_s<<<dim3(1, 8), 256, 0, stream>>>(a2);
  }
  transpose_k<<<(512 * 64 + 255) / 256, 256, 0, stream>>>(ne2b, neT, 512, 64);
  fgemm32(stream, EPI_RELU, ne1b, neT, nullptr, Mbuf, 512, 512, 64, 512,
          nullptr, nullptr, nullptr, nullptr, nullptr, 0, 0, 0);
  softmax512_k<<<512, 256, 0, stream>>>(Mbuf, Gbig, 0);
  softmax512_k<<<512, 256, 0, stream>>>(Mbuf, Gbig + (size_t)1024 * 512, 1);
  fgemm32(stream, EPI_CHEB, Gbig, Gbig, nullptr, Gbig + (size_t)512 * 512,
          512, 512, 512, 512, nullptr, nullptr, nullptr, nullptr, nullptr, 0, 0, 0);
  fgemm32(stream, EPI_CHEB, Gbig + (size_t)1024 * 512, Gbig + (size_t)1024 * 512, nullptr,
          Gbig + (size_t)1536 * 512, 512, 512, 512, 512,
          nullptr, nullptr, nullptr, nullptr, nullptr, 0, 0, 0);

  zero_k<<<(8192 * 64 + 255) / 256, 256, 0, stream>>>(H, 8192 * 64);

  // --- encoder: 12 graph-GRU steps (64-tile SCAT, fused epilogues) ---
  for (int t = 0; t < 12; t++) {
    putxe_k<<<32, 256, 0, stream>>>(in_x + t * 512, X, XG);
    fgemm(stream, EPI_SCAT, Gbig, X, nullptr, nullptr, 2048, 1040, 512, 1088,
          nullptr, XG, nullptr, nullptr, nullptr, 65, 416, 0);
    fgemm32(stream, EPI_SIG, XG, Wgp, in_egb, zr, 8192, 128, 416, 128,
            H, nullptr, nullptr, X, XG, 0, 0, 0);
    fgemm(stream, EPI_SCAT, Gbig, X, nullptr, nullptr, 2048, 1040, 512, 1088,
          nullptr, XG, nullptr, nullptr, nullptr, 65, 416, 0);
    fgemm32(stream, EPI_UPD, XG, Wup, in_eub, nullptr, 8192, 64, 416, 64,
            zr, H, hen, X, XG, 128, 64, t);
  }

  // --- memory attention (f32, index-exact) ---
  fgemm(stream, EPI_NONE, H, in_wq, nullptr, o_query, 8192, 64, 64, 64,
        nullptr, nullptr, nullptr, nullptr, nullptr, 0, 0, 0);
  attmem_k<<<32, 256, 0, stream>>>(o_query, in_mem, o_att, o_hatt, ind);
  gather_pn_k<<<(16 * 512 * 20 * 64 + 255) / 256, 256, 0, stream>>>(
      ind, in_mem, o_pos, o_neg);

  // --- E = h_en @ fc_e_W (before Gbig overwritten) ---
  fgemm(stream, EPI_NONE, hen, in_fce, nullptr, E, 98304, 64, 64, 64,
        nullptr, nullptr, nullptr, nullptr, nullptr, 0, 0, 0);

  // --- decoder graph from h_att[-1] (batch 15), f32 -> bf16 ---
  fgemm(stream, EPI_NONE, o_hatt + (size_t)15 * 512 * 64, in_twe1, nullptr, ne1b,
        512, 64, 64, 64, nullptr, nullptr, nullptr, nullptr, nullptr, 0, 0, 0);
  fgemm(stream, EPI_NONE, o_hatt + (size_t)15 * 512 * 64, in_twe2, nullptr, ne2b,
        512, 64, 64, 64, nullptr, nullptr, nullptr, nullptr, nullptr, 0, 0, 0);
  transpose_k<<<(512 * 64 + 255) / 256, 256, 0, stream>>>(ne2b, neT, 512, 64);
  fgemm32(stream, EPI_RELU, ne1b, neT, nullptr, Mbuf, 512, 512, 64, 512,
          nullptr, nullptr, nullptr, nullptr, nullptr, 0, 0, 0);
  softmax512_k<<<512, 256, 0, stream>>>(Mbuf, tGbig, 0);
  softmax512_k<<<512, 256, 0, stream>>>(Mbuf, tGbig + (size_t)1024 * 512, 1);
  fgemm32(stream, EPI_CHEB, tGbig, tGbig, nullptr, tGbig + (size_t)512 * 512,
          512, 512, 512, 512, nullptr, nullptr, nullptr, nullptr, nullptr, 0, 0, 0);
  fgemm32(stream, EPI_CHEB, tGbig + (size_t)1024 * 512, tGbig + (size_t)1024 * 512, nullptr,
          tGbig + (size_t)1536 * 512, 512, 512, 512, 512,
          nullptr, nullptr, nullptr, nullptr, nullptr, 0, 0, 0);
  f2b_k<<<(2048 * 512 + 255) / 256, 256, 0, stream>>>(tGbig, Gb16, 2048 * 512);

  zeroi_k<<<(8192 * 800 / 2 + 255) / 256, 256, 0, stream>>>((int*)XGb, 8192 * 800 / 2);
  sinit_k<<<(8192 * 128 + 255) / 256, 256, 0, stream>>>(H, o_hatt, S, XT, XGb);

  // --- decoder: 12 graph-GRU steps (fused epilogues) ---
  for (int t = 0; t < 12; t++) {
    putxd_k<<<32, 256, 0, stream>>>(in_ycov + t * 512, XT, XGb);
    mm(stream, EPI_SCAT, Gb16, XT, 2048, 2080, 512, nullptr, nullptr, XGb,
       nullptr, nullptr, nullptr, nullptr, nullptr, 130, 800, 0);
    mm(stream, EPI_SIG, XGb, WTdg, 8192, 256, 800, in_dgb, zr, nullptr,
       nullptr, S, nullptr, XT, XGb, 0, 0, 0);
    mm(stream, EPI_SCAT, Gb16, XT, 2048, 2080, 512, nullptr, nullptr, XGb,
       nullptr, nullptr, nullptr, nullptr, nullptr, 130, 800, 0);
    mm(stream, EPI_UPD, XGb, WTdu, 8192, 128, 800, in_dub, nullptr, nullptr,
       zr, S, nullptr, XT, XGb, 256, 128, 0);
    fgemm32(stream, EPI_NONE, S, in_fcd, nullptr, Dflat, 8192, 64, 128, 64,
            nullptr, nullptr, nullptr, nullptr, nullptr, 0, 0, 0);
    att_dot_k<<<dim3(32, 12), 256, 0, stream>>>(E, Dflat, partial);
    ctxgo_k<<<8192, 64, 0, stream>>>(hen, partial, S, in_pW, in_pb,
                                     XT, XGb, o_out, t);
  }
}